// Round 6
// baseline (193.316 us; speedup 1.0000x reference)
//
#include <hip/hip_runtime.h>
#include <stdint.h>

#define CONF 0.96f
#define IOUT 0.45f
#define NA 25200
#define DIM 85
#define NC 80
#define NIMG 8
#define NCAND 2048
#define CAPRAW 4096
#define NDET 300
#define CSTRIDE 32                    // cnt[img*CSTRIDE]: 128 B between counters

// ---------------- K0: zero per-image candidate counters ----------------
__global__ void k0_zero(int* __restrict__ cnt) {
    cnt[threadIdx.x] = 0;             // launch 256 = NIMG*CSTRIDE
}

// ---------------- K1: coalesced filter, block-aggregated atomics -------
#define APB 112
#define BCAP 256                      // block candidate cap (E=7.3, P(>256)~0)
__global__ __launch_bounds__(256) void k1_filter(
    const float* __restrict__ pred, int* __restrict__ cnt,
    float* __restrict__ raw_s, int* __restrict__ raw_f) {
    __shared__ float lds[APB * DIM];  // 38080 B
    __shared__ float l_s[BCAP];
    __shared__ int   l_f[BCAP];
    __shared__ int   l_cnt, l_base;
    int tid = threadIdx.x;
    int img = blockIdx.y;
    int a0 = blockIdx.x * APB;        // anchor base within this image
    if (tid == 0) l_cnt = 0;

    const float4* src = (const float4*)(pred + ((size_t)img * NA + a0) * DIM);
    float4* dst = (float4*)lds;
    for (int i = tid; i < (APB * DIM / 4); i += 256) dst[i] = src[i];
    __syncthreads();

    // 112*80 = 8960 items over 256 threads (35 iters)
    for (int it = 0; it < (APB * NC / 256); ++it) {
        int w = tid + it * 256;
        int al = w / NC;              // local anchor
        int c = w - al * NC;          // class
        float obj = lds[al * DIM + 4];
        float s = lds[al * DIM + 5 + c] * obj;
        if (s > CONF && obj > CONF) {
            int p = atomicAdd(&l_cnt, 1);          // LDS atomic: cheap
            if (p < BCAP) { l_s[p] = s; l_f[p] = (a0 + al) * NC + c; }
        }
    }
    __syncthreads();
    int c = l_cnt; if (c > BCAP) c = BCAP;
    if (tid == 0) l_base = c ? atomicAdd(&cnt[img * CSTRIDE], c) : 0;
    __syncthreads();
    int base = l_base;
    for (int i = tid; i < c; i += 256) {
        int pos = base + i;
        if (pos < CAPRAW) {
            raw_s[img * CAPRAW + pos] = l_s[i];
            raw_f[img * CAPRAW + pos] = l_f[i];
        }
    }
}

// ---------------- K2: O(n^2) rank sort, LDS-broadcast inner loop -------
// Keys distinct (flat idx in low bits) -> rank is a permutation; scatter
// to rank = exact descending sort, tie semantics identical to top_k.
// R5 lesson: v_readlane broadcast chain = 65 cyc/iter latency-exposed.
// Now: all keys staged in LDS; same-address ds_read_b64 broadcasts (free),
// unroll-8 keeps 8 independent reads in flight. Pad keys are 0 (never >).
__global__ __launch_bounds__(256) void k2_rank(
    const float* __restrict__ pred,
    const int* __restrict__ cnt, int* __restrict__ n_arr,
    const float* __restrict__ raw_s, const int* __restrict__ raw_f,
    float* __restrict__ score, int* __restrict__ label,
    float* __restrict__ ox1, float* __restrict__ oy1,
    float* __restrict__ ox2, float* __restrict__ oy2,
    float* __restrict__ area,
    float* __restrict__ rx1, float* __restrict__ ry1,
    float* __restrict__ rx2, float* __restrict__ ry2) {
    __shared__ uint64_t keys[CAPRAW];             // 32 KB
    int img = blockIdx.y;
    int tid = threadIdx.x;
    int m = cnt[img * CSTRIDE]; if (m > CAPRAW) m = CAPRAW;
    if (blockIdx.x == 0 && tid == 0) n_arr[img] = m < NCAND ? m : NCAND;

    const float* rs = raw_s + img * CAPRAW;
    const int*   rf = raw_f + img * CAPRAW;
    for (int j = tid; j < CAPRAW; j += 256) {
        uint64_t k = 0;
        if (j < m)
            k = ((uint64_t)__float_as_uint(rs[j]) << 32) | (uint32_t)(~(uint32_t)rf[j]);
        keys[j] = k;
    }
    __syncthreads();
    if (blockIdx.x * 256 >= m) return;            // block-uniform exit

    int idx = blockIdx.x * 256 + tid;
    bool valid = idx < m;
    uint64_t my = keys[idx];                      // 0 for invalid threads
    int mt = (m + 7) & ~7;                        // pad keys are 0: never count
    int rank = 0;
#pragma unroll 8
    for (int j = 0; j < mt; ++j) rank += (keys[j] > my) ? 1 : 0;

    if (valid && rank < NCAND) {
        float s = __uint_as_float((uint32_t)(my >> 32));
        uint32_t myf = ~((uint32_t)my);
        int anchor = (int)(myf / NC);
        int lab = (int)(myf - (uint32_t)anchor * NC);
        const float* p = pred + ((size_t)img * NA + anchor) * DIM;
        float cx = p[0], cy = p[1], wv = p[2], hv = p[3];
        float x1 = cx - 0.5f * wv, y1 = cy - 0.5f * hv;
        float x2 = cx + 0.5f * wv, y2 = cy + 0.5f * hv;
        float off = (float)lab * 4.0f;
        size_t o = (size_t)img * NCAND + rank;
        score[o] = s; label[o] = lab;
        rx1[o] = x1; ry1[o] = y1; rx2[o] = x2; ry2[o] = y2;
        float o1 = x1 + off, o2 = y1 + off, o3 = x2 + off, o4 = y2 + off;
        ox1[o] = o1; oy1[o] = o2; ox2[o] = o3; oy2[o] = o4;
        area[o] = (o3 - o1) * (o4 - o2);   // same op order as reference
    }
}

// ---------------- K3: suppression bitmask matrix, LDS-tiled ------------
// 512 blocks x 256 thr. All 2048 j-boxes staged in LDS (float4 + area),
// j >= n ZERO-FILLED: zero box gives inter=0 -> iou=0 exactly (never
// suppresses, never suppressed) so the hot loop has NO n-guard and fully
// unrolls. Each wave: 8 uniform i's (broadcast LDS read) x 32 b-iters.
// Lane L, bit b <-> j = L + 64*b (same layout as before).
#define ITILE 32
__global__ __launch_bounds__(256) void k3_mask(
    const int* __restrict__ n_arr,
    const float* __restrict__ ox1, const float* __restrict__ oy1,
    const float* __restrict__ ox2, const float* __restrict__ oy2,
    const float* __restrict__ area, uint32_t* __restrict__ mask) {
    __shared__ float4 jb[NCAND];      // 32 KB
    __shared__ float  ja[NCAND];      // 8 KB
    int img = blockIdx.y;
    int n = n_arr[img];
    int tid = threadIdx.x;
    size_t base = (size_t)img * NCAND;
    for (int j = tid; j < NCAND; j += 256) {
        float4 v = make_float4(0.f, 0.f, 0.f, 0.f);
        float ar = 0.f;
        if (j < n) {
            v = make_float4(ox1[base + j], oy1[base + j], ox2[base + j], oy2[base + j]);
            ar = area[base + j];
        }
        jb[j] = v; ja[j] = ar;
    }
    __syncthreads();

    int lane = tid & 63, wv = tid >> 6;
    int i0 = blockIdx.x * ITILE + wv * (ITILE / 4);
    for (int ii = 0; ii < ITILE / 4; ++ii) {
        int i = i0 + ii;                           // wave-uniform
        float4 a = jb[i];                          // broadcast LDS read
        float aar = ja[i];
        uint32_t word = 0;
#pragma unroll
        for (int b = 0; b < 32; ++b) {
            int j = lane + (b << 6);
            float4 bb = jb[j];
            float bar = ja[j];
            float ltx = fmaxf(a.x, bb.x), lty = fmaxf(a.y, bb.y);
            float rbx = fminf(a.z, bb.z), rby = fminf(a.w, bb.w);
            float w2 = fmaxf(rbx - ltx, 0.0f), h2 = fmaxf(rby - lty, 0.0f);
            float inter = w2 * h2;
            float iou = inter / (aar + bar - inter + 1e-9f);
            word |= (iou > IOUT && j > i) ? (1u << b) : 0u;
        }
        mask[(base + i) * 64 + lane] = word;
    }
}

// ---------------- K4: serial greedy scan + top-300 output --------------
// One wave per image; early stop at 300 kept (see R3 notes).
__global__ void k4_scan(const int* __restrict__ n_arr,
                        const uint32_t* __restrict__ mask,
                        const float* __restrict__ score, const int* __restrict__ label,
                        const float* __restrict__ rx1, const float* __restrict__ ry1,
                        const float* __restrict__ rx2, const float* __restrict__ ry2,
                        float* __restrict__ out) {
    int img = blockIdx.x;
    int lane = threadIdx.x;   // 64 threads = 1 wave
    int n = n_arr[img];
    size_t cbase = (size_t)img * NCAND;
    const uint32_t* rowp = mask + cbase * 64 + lane;
    float* outp = out + (size_t)img * NDET * 6;

    uint32_t removed = 0;
    int kcnt = 0;
    constexpr int PF = 32;           // prefetch depth (static indices -> regs)
    uint32_t buf[PF];
#pragma unroll
    for (int k = 0; k < PF; ++k) buf[k] = rowp[(size_t)k * 64];
    for (int ib = 0; ib < n; ib += PF) {
#pragma unroll
        for (int k = 0; k < PF; ++k) {
            int i = ib + k;
            uint32_t row = buf[k];
            int pi = i + PF; if (pi > NCAND - 1) pi = NCAND - 1;  // uniform, SALU
            buf[k] = rowp[(size_t)pi * 64];     // clamped dup never consumed
            uint32_t w = (uint32_t)__builtin_amdgcn_readlane((int)removed, i & 63);
            uint32_t kept = ((w >> (i >> 6)) & 1u) ^ 1u;
            kcnt += (int)kept;                   // scalar (phantom i>=n harmless)
            removed |= row & (0u - kept);        // row==0 when i>=n -> no-op
        }
        if (kcnt >= NDET) break;                 // uniform early stop
    }

    // Emit kept candidates in sorted order (rank = #kept with smaller j).
    int bsum = 0;
    for (int b = 0; b < 32; ++b) {
        int j = lane + (b << 6);
        bool kept = (j < n) && (((removed >> b) & 1u) == 0u);
        unsigned long long m64 = __ballot(kept);
        if (kept) {
            int r = bsum + (int)__popcll(m64 & ((1ull << lane) - 1ull));
            if (r < NDET) {
                float* o = outp + (size_t)r * 6;
                o[0] = rx1[cbase + j]; o[1] = ry1[cbase + j];
                o[2] = rx2[cbase + j]; o[3] = ry2[cbase + j];
                o[4] = score[cbase + j]; o[5] = (float)label[cbase + j];
            }
        }
        bsum += (int)__popcll(m64);
        if (bsum >= NDET) break;         // uniform across the wave
    }
    int nk = bsum < NDET ? bsum : NDET;
    for (int idx = nk * 6 + lane; idx < NDET * 6; idx += 64) outp[idx] = 0.0f;
}

// ---------------- launch ----------------
extern "C" void kernel_launch(void* const* d_in, const int* in_sizes, int n_in,
                              void* d_out, int out_size, void* d_ws, size_t ws_size,
                              hipStream_t stream) {
    const float* pred = (const float*)d_in[0];
    float* out = (float*)d_out;
    char* w = (char*)d_ws;

    const size_t A_CNT = 0;                                // 8*32 ints (padded)
    const size_t A_N   = 1024;                             // 8 ints
    const size_t A_RS  = 1280;
    const size_t SZ_RAW = (size_t)NIMG * CAPRAW * 4;       // 128 KiB
    const size_t A_RF  = A_RS + SZ_RAW;
    const size_t SA    = A_RF + SZ_RAW;
    const size_t SZ_S  = (size_t)NIMG * NCAND * 4;         // 64 KiB each

    int*   cnt   = (int*)(w + A_CNT);
    int*   n_arr = (int*)(w + A_N);
    float* raw_s = (float*)(w + A_RS);
    int*   raw_f = (int*)(w + A_RF);
    float* score = (float*)(w + SA + 0 * SZ_S);
    int*   label = (int*)(w + SA + 1 * SZ_S);
    float* ox1   = (float*)(w + SA + 2 * SZ_S);
    float* oy1   = (float*)(w + SA + 3 * SZ_S);
    float* ox2   = (float*)(w + SA + 4 * SZ_S);
    float* oy2   = (float*)(w + SA + 5 * SZ_S);
    float* area  = (float*)(w + SA + 6 * SZ_S);
    float* rx1   = (float*)(w + SA + 7 * SZ_S);
    float* ry1   = (float*)(w + SA + 8 * SZ_S);
    float* rx2   = (float*)(w + SA + 9 * SZ_S);
    float* ry2   = (float*)(w + SA + 10 * SZ_S);
    uint32_t* mask = (uint32_t*)(w + SA + 11 * SZ_S);      // 8*2048*64*4 = 4 MiB

    k0_zero<<<1, NIMG * CSTRIDE, 0, stream>>>(cnt);
    dim3 g1(NA / APB, NIMG);                               // 225 x 8
    k1_filter<<<g1, 256, 0, stream>>>(pred, cnt, raw_s, raw_f);
    dim3 g2(CAPRAW / 256, NIMG);                           // 16 x 8
    k2_rank<<<g2, 256, 0, stream>>>(pred, cnt, n_arr, raw_s, raw_f,
        score, label, ox1, oy1, ox2, oy2, area, rx1, ry1, rx2, ry2);
    dim3 g3(NCAND / ITILE, NIMG);                          // 64 x 8
    k3_mask<<<g3, 256, 0, stream>>>(n_arr, ox1, oy1, ox2, oy2, area, mask);
    k4_scan<<<NIMG, 64, 0, stream>>>(n_arr, mask, score, label,
        rx1, ry1, rx2, ry2, out);
}

// Round 7
// 180.071 us; speedup vs baseline: 1.0736x; 1.0736x over previous
//
#include <hip/hip_runtime.h>
#include <stdint.h>

#define CONF 0.96f
#define IOUT 0.45f
#define NA 25200
#define DIM 85
#define NC 80
#define NIMG 8
#define NCAND 2048
#define CAPRAW 4096
#define NDET 300
#define CSTRIDE 32                    // cnt[img*CSTRIDE]: 128 B between counters
#define CH 64                         // k3 tile edge
#define NCH (NCAND / CH)              // 32 chunks
#define NTPAIR ((NCH * (NCH + 1)) / 2)  // 528 upper-triangle tile pairs

// ---------------- K1: coalesced filter, block-aggregated atomics -------
#define APB 112
#define BCAP 256                      // block candidate cap (E=7.3, P(>256)~0)
__global__ __launch_bounds__(256) void k1_filter(
    const float* __restrict__ pred, int* __restrict__ cnt,
    float* __restrict__ raw_s, int* __restrict__ raw_f) {
    __shared__ float lds[APB * DIM];  // 38080 B
    __shared__ float l_s[BCAP];
    __shared__ int   l_f[BCAP];
    __shared__ int   l_cnt, l_base;
    int tid = threadIdx.x;
    int img = blockIdx.y;
    int a0 = blockIdx.x * APB;        // anchor base within this image
    if (tid == 0) l_cnt = 0;

    const float4* src = (const float4*)(pred + ((size_t)img * NA + a0) * DIM);
    float4* dst = (float4*)lds;
    for (int i = tid; i < (APB * DIM / 4); i += 256) dst[i] = src[i];
    __syncthreads();

    // 112*80 = 8960 items over 256 threads (35 iters)
    for (int it = 0; it < (APB * NC / 256); ++it) {
        int w = tid + it * 256;
        int al = w / NC;              // local anchor
        int c = w - al * NC;          // class
        float obj = lds[al * DIM + 4];
        float s = lds[al * DIM + 5 + c] * obj;
        if (s > CONF && obj > CONF) {
            int p = atomicAdd(&l_cnt, 1);          // LDS atomic: cheap
            if (p < BCAP) { l_s[p] = s; l_f[p] = (a0 + al) * NC + c; }
        }
    }
    __syncthreads();
    int c = l_cnt; if (c > BCAP) c = BCAP;
    if (tid == 0) l_base = c ? atomicAdd(&cnt[img * CSTRIDE], c) : 0;
    __syncthreads();
    int base = l_base;
    for (int i = tid; i < c; i += 256) {
        int pos = base + i;
        if (pos < CAPRAW) {
            raw_s[img * CAPRAW + pos] = l_s[i];
            raw_f[img * CAPRAW + pos] = l_f[i];
        }
    }
}

// ---------------- K2: O(n^2) rank sort, LDS-broadcast inner loop -------
// Keys distinct (flat idx in low bits) -> rank is a permutation; scatter
// to rank = exact descending sort, tie semantics identical to top_k.
__global__ __launch_bounds__(256) void k2_rank(
    const float* __restrict__ pred,
    const int* __restrict__ cnt, int* __restrict__ n_arr,
    const float* __restrict__ raw_s, const int* __restrict__ raw_f,
    float* __restrict__ score, int* __restrict__ label,
    float* __restrict__ ox1, float* __restrict__ oy1,
    float* __restrict__ ox2, float* __restrict__ oy2,
    float* __restrict__ area,
    float* __restrict__ rx1, float* __restrict__ ry1,
    float* __restrict__ rx2, float* __restrict__ ry2) {
    __shared__ uint64_t keys[CAPRAW];             // 32 KB
    int img = blockIdx.y;
    int tid = threadIdx.x;
    int m = cnt[img * CSTRIDE]; if (m > CAPRAW) m = CAPRAW;
    if (blockIdx.x == 0 && tid == 0) n_arr[img] = m < NCAND ? m : NCAND;

    const float* rs = raw_s + img * CAPRAW;
    const int*   rf = raw_f + img * CAPRAW;
    for (int j = tid; j < CAPRAW; j += 256) {
        uint64_t k = 0;
        if (j < m)
            k = ((uint64_t)__float_as_uint(rs[j]) << 32) | (uint32_t)(~(uint32_t)rf[j]);
        keys[j] = k;
    }
    __syncthreads();
    if (blockIdx.x * 256 >= m) return;            // block-uniform exit

    int idx = blockIdx.x * 256 + tid;
    bool valid = idx < m;
    uint64_t my = keys[idx];                      // 0 for invalid threads
    int mt = (m + 7) & ~7;                        // pad keys are 0: never count
    int rank = 0;
#pragma unroll 8
    for (int j = 0; j < mt; ++j) rank += (keys[j] > my) ? 1 : 0;

    if (valid && rank < NCAND) {
        float s = __uint_as_float((uint32_t)(my >> 32));
        uint32_t myf = ~((uint32_t)my);
        int anchor = (int)(myf / NC);
        int lab = (int)(myf - (uint32_t)anchor * NC);
        const float* p = pred + ((size_t)img * NA + anchor) * DIM;
        float cx = p[0], cy = p[1], wv = p[2], hv = p[3];
        float x1 = cx - 0.5f * wv, y1 = cy - 0.5f * hv;
        float x2 = cx + 0.5f * wv, y2 = cy + 0.5f * hv;
        float off = (float)lab * 4.0f;
        size_t o = (size_t)img * NCAND + rank;
        score[o] = s; label[o] = lab;
        rx1[o] = x1; ry1[o] = y1; rx2[o] = x2; ry2[o] = y2;
        float o1 = x1 + off, o2 = y1 + off, o3 = x2 + off, o4 = y2 + off;
        ox1[o] = o1; oy1[o] = o2; ox2[o] = o3; oy2[o] = o4;
        area[o] = (o3 - o1) * (o4 - o2);   // same op order as reference
    }
}

// ---------------- K3: upper-triangle 64x64 tiles (torchvision-style) ---
// Grid (528 tile-pairs, 8 img), 1 wave/block. Thread t owns row i=ci*64+t,
// loops 64 LDS-broadcast j's, emits one u64 word. Only cj>=ci tiles run
// (below-diagonal words come from the 4 MiB memset); tiles past n exit.
// j>=n / i>=n entries are zero boxes -> inter=0 -> iou=0 exactly, never
// suppress. BLOCKED mask layout: row i word c (u64) covers j in
// [64c,64c+64); as u32 view lane l owns j in [32l, 32l+32).
__global__ __launch_bounds__(64) void k3_mask(
    const int* __restrict__ n_arr,
    const float* __restrict__ ox1, const float* __restrict__ oy1,
    const float* __restrict__ ox2, const float* __restrict__ oy2,
    const float* __restrict__ area, uint64_t* __restrict__ mask64) {
    int img = blockIdx.y;
    int n = n_arr[img];
    int p = blockIdx.x, ci = 0;                   // triangle decode (scalar)
    while (p >= NCH - ci) { p -= NCH - ci; ++ci; }
    int cj = ci + p;
    if (ci * CH >= n) return;                     // rows never read by k4
    int t = threadIdx.x;
    size_t base = (size_t)img * NCAND;
    __shared__ float jx1[CH], jy1[CH], jx2[CH], jy2[CH], jar[CH];
    {
        int j = cj * CH + t;
        float x1 = 0.f, y1 = 0.f, x2 = 0.f, y2 = 0.f, ar = 0.f;
        if (j < n) {
            x1 = ox1[base + j]; y1 = oy1[base + j];
            x2 = ox2[base + j]; y2 = oy2[base + j]; ar = area[base + j];
        }
        jx1[t] = x1; jy1[t] = y1; jx2[t] = x2; jy2[t] = y2; jar[t] = ar;
    }
    __syncthreads();
    int i = ci * CH + t;
    float ax1 = 0.f, ay1 = 0.f, ax2 = 0.f, ay2 = 0.f, aar = 0.f;
    if (i < n) {
        ax1 = ox1[base + i]; ay1 = oy1[base + i];
        ax2 = ox2[base + i]; ay2 = oy2[base + i]; aar = area[base + i];
    }
    int jg0 = cj * CH;
    uint64_t w = 0;
#pragma unroll 8
    for (int jj = 0; jj < CH; ++jj) {
        float ltx = fmaxf(ax1, jx1[jj]), lty = fmaxf(ay1, jy1[jj]);
        float rbx = fminf(ax2, jx2[jj]), rby = fminf(ay2, jy2[jj]);
        float ww = fmaxf(rbx - ltx, 0.f), hh = fmaxf(rby - lty, 0.f);
        float inter = ww * hh;
        float iou = inter / (aar + jar[jj] - inter + 1e-9f);  // keep IEEE div: exact
        w |= (iou > IOUT && (jg0 + jj) > i) ? (1ull << jj) : 0ull;
    }
    mask64[(base + (size_t)i) * NCH + cj] = w;
}

// ---------------- K4: serial greedy scan + top-300 output --------------
// One wave per image; early stop at 300 kept. Blocked layout: removed
// register lane l holds bits j = 32l + b.
__global__ void k4_scan(const int* __restrict__ n_arr,
                        const uint32_t* __restrict__ mask,
                        const float* __restrict__ score, const int* __restrict__ label,
                        const float* __restrict__ rx1, const float* __restrict__ ry1,
                        const float* __restrict__ rx2, const float* __restrict__ ry2,
                        float* __restrict__ out) {
    int img = blockIdx.x;
    int lane = threadIdx.x;   // 64 threads = 1 wave
    int n = n_arr[img];
    size_t cbase = (size_t)img * NCAND;
    const uint32_t* rowp = mask + cbase * 64 + lane;
    float* outp = out + (size_t)img * NDET * 6;

    uint32_t removed = 0;
    int kcnt = 0;
    constexpr int PF = 32;           // prefetch depth (static indices -> regs)
    uint32_t buf[PF];
#pragma unroll
    for (int k = 0; k < PF; ++k) buf[k] = rowp[(size_t)k * 64];
    for (int ib = 0; ib < n; ib += PF) {
#pragma unroll
        for (int k = 0; k < PF; ++k) {
            int i = ib + k;
            uint32_t row = buf[k];
            int pi = i + PF; if (pi > NCAND - 1) pi = NCAND - 1;  // uniform, SALU
            buf[k] = rowp[(size_t)pi * 64];     // clamped dup never consumed
            // kept(i)? blocked layout: word at lane i>>5, bit i&31. i uniform.
            uint32_t w = (uint32_t)__builtin_amdgcn_readlane((int)removed, i >> 5);
            uint32_t kept = ((w >> (i & 31)) & 1u) ^ 1u;
            kcnt += (int)kept;                   // phantom i>=n harmless (row 0)
            removed |= row & (0u - kept);
        }
        if (kcnt >= NDET) break;                 // uniform early stop
    }

    // Emit kept in sorted order. Lane l covers j in [32l, 32l+32) ->
    // global rank = exclusive lane-prefix of popcounts + in-word prefix.
    int j0 = lane << 5;
    uint32_t vmask = (j0 + 32 <= n) ? 0xffffffffu
                   : (j0 >= n ? 0u : ((1u << (n - j0)) - 1u));
    uint32_t keptw = ~removed & vmask;
    int cnt = __popc(keptw);
    int pre = cnt;
    for (int d = 1; d < 64; d <<= 1) {           // inclusive shuffle prefix
        int tv = __shfl_up(pre, d);
        if (lane >= d) pre += tv;
    }
    int total = __shfl(pre, 63);
    int r = pre - cnt;                           // exclusive prefix
    uint32_t wv = keptw;
    while (wv) {
        int b = __builtin_ctz(wv);
        wv &= wv - 1;
        if (r >= NDET) break;
        int j = j0 + b;
        float* o = outp + (size_t)r * 6;
        o[0] = rx1[cbase + j]; o[1] = ry1[cbase + j];
        o[2] = rx2[cbase + j]; o[3] = ry2[cbase + j];
        o[4] = score[cbase + j]; o[5] = (float)label[cbase + j];
        ++r;
    }
    int nk = total < NDET ? total : NDET;
    for (int idx = nk * 6 + lane; idx < NDET * 6; idx += 64) outp[idx] = 0.0f;
}

// ---------------- launch ----------------
extern "C" void kernel_launch(void* const* d_in, const int* in_sizes, int n_in,
                              void* d_out, int out_size, void* d_ws, size_t ws_size,
                              hipStream_t stream) {
    const float* pred = (const float*)d_in[0];
    float* out = (float*)d_out;
    char* w = (char*)d_ws;

    const size_t A_CNT = 0;                                // 8*32 ints (padded)
    const size_t A_N   = 1024;                             // 8 ints
    const size_t A_RS  = 1280;
    const size_t SZ_RAW = (size_t)NIMG * CAPRAW * 4;       // 128 KiB
    const size_t A_RF  = A_RS + SZ_RAW;
    const size_t SA    = A_RF + SZ_RAW;
    const size_t SZ_S  = (size_t)NIMG * NCAND * 4;         // 64 KiB each

    int*   cnt   = (int*)(w + A_CNT);
    int*   n_arr = (int*)(w + A_N);
    float* raw_s = (float*)(w + A_RS);
    int*   raw_f = (int*)(w + A_RF);
    float* score = (float*)(w + SA + 0 * SZ_S);
    int*   label = (int*)(w + SA + 1 * SZ_S);
    float* ox1   = (float*)(w + SA + 2 * SZ_S);
    float* oy1   = (float*)(w + SA + 3 * SZ_S);
    float* ox2   = (float*)(w + SA + 4 * SZ_S);
    float* oy2   = (float*)(w + SA + 5 * SZ_S);
    float* area  = (float*)(w + SA + 6 * SZ_S);
    float* rx1   = (float*)(w + SA + 7 * SZ_S);
    float* ry1   = (float*)(w + SA + 8 * SZ_S);
    float* rx2   = (float*)(w + SA + 9 * SZ_S);
    float* ry2   = (float*)(w + SA + 10 * SZ_S);
    uint64_t* mask64 = (uint64_t*)(w + SA + 11 * SZ_S);    // 8*2048*32*8 = 4 MiB
    uint32_t* mask32 = (uint32_t*)mask64;

    hipMemsetAsync(cnt, 0, NIMG * CSTRIDE * sizeof(int), stream);
    hipMemsetAsync(mask64, 0, (size_t)NIMG * NCAND * NCH * 8, stream);
    dim3 g1(NA / APB, NIMG);                               // 225 x 8
    k1_filter<<<g1, 256, 0, stream>>>(pred, cnt, raw_s, raw_f);
    dim3 g2(CAPRAW / 256, NIMG);                           // 16 x 8
    k2_rank<<<g2, 256, 0, stream>>>(pred, cnt, n_arr, raw_s, raw_f,
        score, label, ox1, oy1, ox2, oy2, area, rx1, ry1, rx2, ry2);
    dim3 g3(NTPAIR, NIMG);                                 // 528 x 8
    k3_mask<<<g3, CH, 0, stream>>>(n_arr, ox1, oy1, ox2, oy2, area, mask64);
    k4_scan<<<NIMG, 64, 0, stream>>>(n_arr, mask32, score, label,
        rx1, ry1, rx2, ry2, out);
}